// Round 16
// baseline (217.734 us; speedup 1.0000x reference)
//
#include <hip/hip_runtime.h>
#include <hip/hip_bf16.h>

#define NN 100000
#define NE 1600000
#define DD 64
#define NCOARSE 196         // 512-node coarse buckets (node>>9)
#define GEMM_TILES 3125     // NN/32 exactly (32-row tiles, no tail)
#define PLACE_EPB 2048
#define PLACE_BLOCKS 782    // ceil(NE/2048)
#define LCNT_STRIDE 800     // padded row stride of lcntT
#define GATHER_BLOCKS 12500 // NN/8
#define PRED_BLOCKS 125     // 12500/100

__device__ inline unsigned short f2bf(float f) {
    __hip_bfloat16 h = __float2bfloat16(f);
    unsigned short s; __builtin_memcpy(&s, &h, 2); return s;
}
// decode packed edge: src = p & 0x1FFFF;  w = bf15<<16 (sign 0)
__device__ inline float pw(unsigned p) { return __uint_as_float((p & 0xFFFE0000u) >> 1); }

// ---------------- K1: per-block coarse histogram ----------------
__global__ __launch_bounds__(256) void k_hist(const int* __restrict__ edst,
                                              int* __restrict__ lcntT) {
    __shared__ int h[NCOARSE];
    for (int i = threadIdx.x; i < NCOARSE; i += 256) h[i] = 0;
    __syncthreads();
    const int e0 = blockIdx.x * PLACE_EPB;
#pragma unroll
    for (int k = 0; k < 8; ++k) {
        int e = e0 + k * 256 + threadIdx.x;
        if (e < NE) atomicAdd(&h[edst[e] >> 9], 1);
    }
    __syncthreads();
    for (int i = threadIdx.x; i < NCOARSE; i += 256)
        lcntT[i * LCNT_STRIDE + blockIdx.x] = h[i];
}

// ---------------- K2: in-place exclusive scan of each bucket's block counts ----------------
__global__ __launch_bounds__(256) void k_colscan(int* __restrict__ lcntT,
                                                 int* __restrict__ cnt) {
    int* col = lcntT + blockIdx.x * LCNT_STRIDE;
    const int t = threadIdx.x, base = t * 4;
    int v[4], s = 0;
#pragma unroll
    for (int j = 0; j < 4; ++j) {
        v[j] = (base + j < PLACE_BLOCKS) ? col[base + j] : 0;
        s += v[j];
    }
    __shared__ int sc[256];
    sc[t] = s; __syncthreads();
    for (int o = 1; o < 256; o <<= 1) {
        int u = (t >= o) ? sc[t - o] : 0;
        __syncthreads();
        sc[t] += u;
        __syncthreads();
    }
    int run = sc[t] - s;
#pragma unroll
    for (int j = 0; j < 4; ++j) {
        if (base + j < PLACE_BLOCKS) col[base + j] = run;
        run += v[j];
    }
    if (t == 255) cnt[blockIdx.x] = sc[255];
}

// ---------------- K3: exclusive scan of 196 coarse totals ----------------
__global__ __launch_bounds__(256) void k_scan196(const int* __restrict__ cnt,
                                                 int* __restrict__ cstart,
                                                 int* __restrict__ bstart) {
    __shared__ int sc[256];
    const int t = threadIdx.x;
    const int v = (t < NCOARSE) ? cnt[t] : 0;
    sc[t] = v; __syncthreads();
    for (int o = 1; o < 256; o <<= 1) {
        int u = (t >= o) ? sc[t - o] : 0;
        __syncthreads();
        sc[t] += u;
        __syncthreads();
    }
    if (t < NCOARSE) cstart[t] = sc[t] - v;
    if (t == 0) { cstart[NCOARSE] = NE; bstart[NN] = NE; }
}

// ---------------- K4: fused  support = x@W (32-row tiles, blocks [0,3125))  +  edge scatter ----------------
__global__ __launch_bounds__(256) void k_gemm_scatter(const float* __restrict__ x,
                                                      const float* __restrict__ Wg,
                                                      unsigned* __restrict__ support2,
                                                      const int* __restrict__ esrc,
                                                      const int* __restrict__ edst,
                                                      const float* __restrict__ ew,
                                                      const int* __restrict__ cstart,
                                                      const int* __restrict__ lcntT,
                                                      int2* __restrict__ permA) {
    if (blockIdx.x >= GEMM_TILES) {
        const int blk = blockIdx.x - GEMM_TILES;     // 0..781
        __shared__ int loff[NCOARSE];
        for (int i = threadIdx.x; i < NCOARSE; i += 256)
            loff[i] = cstart[i] + lcntT[i * LCNT_STRIDE + blk];
        __syncthreads();
        const int e0 = blk * PLACE_EPB;
#pragma unroll
        for (int k = 0; k < 8; ++k) {
            int e = e0 + k * 256 + threadIdx.x;
            if (e < NE) {
                int d = edst[e];
                int p = atomicAdd(&loff[d >> 9], 1);
                permA[p] = make_int2(esrc[e] | ((d & 511) << 17), __float_as_int(ew[e]));
            }
        }
        return;
    }

    __shared__ float Ws[DD * DD];   // 16 KB
    __shared__ float Xs[32 * DD];   // 8 KB
    const int r0 = blockIdx.x * 32; // always full: 3125*32 == NN

    for (int i = threadIdx.x; i < DD * DD / 4; i += 256)
        ((float4*)Ws)[i] = ((const float4*)Wg)[i];
    const float4* xg = (const float4*)(x + (size_t)r0 * DD);
    for (int i = threadIdx.x; i < 32 * 16; i += 256)
        ((float4*)Xs)[i] = xg[i];
    __syncthreads();

    const int wave = threadIdx.x >> 6, lane = threadIdx.x & 63;
    const int half = lane >> 5, hl = lane & 31;
    const int rbase = wave * 8 + half * 4;   // 4 rows per half-wave

    float acc0[4] = {0.f, 0.f, 0.f, 0.f};
    float acc1[4] = {0.f, 0.f, 0.f, 0.f};
#pragma unroll 4
    for (int k = 0; k < DD; k += 4) {
        float2 w0 = *(const float2*)&Ws[(k + 0) * DD + 2 * hl];
        float2 w1 = *(const float2*)&Ws[(k + 1) * DD + 2 * hl];
        float2 w2 = *(const float2*)&Ws[(k + 2) * DD + 2 * hl];
        float2 w3 = *(const float2*)&Ws[(k + 3) * DD + 2 * hl];
#pragma unroll
        for (int r = 0; r < 4; ++r) {
            float4 xv = *(const float4*)&Xs[(rbase + r) * DD + k];
            acc0[r] = fmaf(xv.x, w0.x, acc0[r]); acc1[r] = fmaf(xv.x, w0.y, acc1[r]);
            acc0[r] = fmaf(xv.y, w1.x, acc0[r]); acc1[r] = fmaf(xv.y, w1.y, acc1[r]);
            acc0[r] = fmaf(xv.z, w2.x, acc0[r]); acc1[r] = fmaf(xv.z, w2.y, acc1[r]);
            acc0[r] = fmaf(xv.w, w3.x, acc0[r]); acc1[r] = fmaf(xv.w, w3.y, acc1[r]);
        }
    }
#pragma unroll
    for (int r = 0; r < 4; ++r) {
        unsigned p = (unsigned)f2bf(acc0[r]) | ((unsigned)f2bf(acc1[r]) << 16);
        support2[(size_t)(r0 + rbase + r) * 32 + hl] = p;
    }
}

// ---------------- K5: placeB — per-node CSR within 512-node bucket; 4B packed entries ----------------
__global__ __launch_bounds__(1024) void k_placeB(const int* __restrict__ cstart,
                                                 const int2* __restrict__ permA,
                                                 unsigned* __restrict__ perm,
                                                 int* __restrict__ bstart) {
    __shared__ int sc[512], loff[512], wtot[8];
    const int c = blockIdx.x, t = threadIdx.x;
    const int wave = t >> 6, lane = t & 63;
    const int cs = cstart[c], ce = cstart[c + 1];
    if (t < 512) sc[t] = 0;
    __syncthreads();
    for (int j = cs + t; j < ce; j += 1024)
        atomicAdd(&sc[(permA[j].x >> 17) & 511], 1);
    __syncthreads();
    int v = 0, xv = 0;
    if (wave < 8) {
        v = sc[t];
        xv = v;
#pragma unroll
        for (int o = 1; o < 64; o <<= 1) {
            int u = __shfl_up(xv, o, 64);
            if (lane >= o) xv += u;
        }
        if (lane == 63) wtot[wave] = xv;
    }
    __syncthreads();
    if (t < 8) {
        int w = wtot[t], xw = w;
#pragma unroll
        for (int o = 1; o < 8; o <<= 1) {
            int u = __shfl_up(xw, o, 64);
            if (t >= o) xw += u;
        }
        wtot[t] = xw - w;
    }
    __syncthreads();
    if (wave < 8) {
        const int base = cs + wtot[wave] + xv - v;
        loff[t] = base;
        const int node = c * 512 + t;
        if (node < NN) bstart[node] = base;
    }
    __syncthreads();
    for (int j = cs + t; j < ce; j += 1024) {
        int2 m = permA[j];
        int p = atomicAdd(&loff[(m.x >> 17) & 511], 1);
        unsigned wb = (unsigned)(f2bf(__int_as_float(m.y)) & 0x7FFF);   // bf16-RNE, sign 0
        perm[p] = (unsigned)(m.x & 0x1FFFF) | (wb << 17);
    }
}

// ---------------- K6: gather + fused per-block column stats ----------------
// 512 thr (8 waves), wave per node; 8-lane subgroup = one edge, lane q covers cols 8q..8q+7
__global__ __launch_bounds__(512) void k_gather(const int* __restrict__ bstart,
                                                const unsigned* __restrict__ perm,
                                                const uint4* __restrict__ support4,
                                                float* __restrict__ out,
                                                float* __restrict__ pstat) {
    const int wave = threadIdx.x >> 6, lane = threadIdx.x & 63;
    const int sub = lane >> 3, q = lane & 7;
    const int d = blockIdx.x * 8 + wave;            // grid = NN/8 exactly
    const int bs = bstart[d], be = bstart[d + 1];
    float acc[8] = {0.f, 0.f, 0.f, 0.f, 0.f, 0.f, 0.f, 0.f};
    int j0 = bs;
    for (; j0 + 15 < be; j0 += 16) {                // 2 loads in flight per lane
        unsigned mA = perm[j0 + sub];
        unsigned mB = perm[j0 + 8 + sub];
        uint4 pA = support4[(size_t)(mA & 0x1FFFF) * 8 + q];
        uint4 pB = support4[(size_t)(mB & 0x1FFFF) * 8 + q];
        float wA = pw(mA), wB = pw(mB);
        acc[0] = fmaf(wA, __uint_as_float(pA.x << 16), acc[0]);
        acc[1] = fmaf(wA, __uint_as_float(pA.x & 0xffff0000u), acc[1]);
        acc[2] = fmaf(wA, __uint_as_float(pA.y << 16), acc[2]);
        acc[3] = fmaf(wA, __uint_as_float(pA.y & 0xffff0000u), acc[3]);
        acc[4] = fmaf(wA, __uint_as_float(pA.z << 16), acc[4]);
        acc[5] = fmaf(wA, __uint_as_float(pA.z & 0xffff0000u), acc[5]);
        acc[6] = fmaf(wA, __uint_as_float(pA.w << 16), acc[6]);
        acc[7] = fmaf(wA, __uint_as_float(pA.w & 0xffff0000u), acc[7]);
        acc[0] = fmaf(wB, __uint_as_float(pB.x << 16), acc[0]);
        acc[1] = fmaf(wB, __uint_as_float(pB.x & 0xffff0000u), acc[1]);
        acc[2] = fmaf(wB, __uint_as_float(pB.y << 16), acc[2]);
        acc[3] = fmaf(wB, __uint_as_float(pB.y & 0xffff0000u), acc[3]);
        acc[4] = fmaf(wB, __uint_as_float(pB.z << 16), acc[4]);
        acc[5] = fmaf(wB, __uint_as_float(pB.z & 0xffff0000u), acc[5]);
        acc[6] = fmaf(wB, __uint_as_float(pB.w << 16), acc[6]);
        acc[7] = fmaf(wB, __uint_as_float(pB.w & 0xffff0000u), acc[7]);
    }
    for (; j0 < be; j0 += 8) {                      // ≤2 guarded tail iterations
        if (j0 + sub < be) {
            unsigned m = perm[j0 + sub];
            uint4 p = support4[(size_t)(m & 0x1FFFF) * 8 + q];
            float w = pw(m);
            acc[0] = fmaf(w, __uint_as_float(p.x << 16), acc[0]);
            acc[1] = fmaf(w, __uint_as_float(p.x & 0xffff0000u), acc[1]);
            acc[2] = fmaf(w, __uint_as_float(p.y << 16), acc[2]);
            acc[3] = fmaf(w, __uint_as_float(p.y & 0xffff0000u), acc[3]);
            acc[4] = fmaf(w, __uint_as_float(p.z << 16), acc[4]);
            acc[5] = fmaf(w, __uint_as_float(p.z & 0xffff0000u), acc[5]);
            acc[6] = fmaf(w, __uint_as_float(p.w << 16), acc[6]);
            acc[7] = fmaf(w, __uint_as_float(p.w & 0xffff0000u), acc[7]);
        }
    }
#pragma unroll
    for (int i = 0; i < 8; ++i) {
        acc[i] += __shfl_xor(acc[i], 8, 64);
        acc[i] += __shfl_xor(acc[i], 16, 64);
        acc[i] += __shfl_xor(acc[i], 32, 64);
    }

    __shared__ float red[2][8][DD];   // 4 KB
    if (sub == 0) {
        float* op = out + (size_t)d * DD + q * 8;
        *(float4*)op = make_float4(acc[0], acc[1], acc[2], acc[3]);
        *(float4*)(op + 4) = make_float4(acc[4], acc[5], acc[6], acc[7]);
#pragma unroll
        for (int i = 0; i < 8; ++i) {
            red[0][wave][q * 8 + i] = acc[i];
            red[1][wave][q * 8 + i] = acc[i] * acc[i];
        }
    }
    __syncthreads();
    if (threadIdx.x < 2 * DD) {       // per-block column partials (8 rows)
        const int t = threadIdx.x, part = t >> 6, c = t & 63;
        float v = 0.f;
#pragma unroll
        for (int w = 0; w < 8; ++w) v += red[part][w][c];
        pstat[(size_t)blockIdx.x * 2 * DD + t] = v;
    }
}

// ---------------- K7: stage-1 reduce of 12500 block partials -> 125 rows ----------------
__global__ __launch_bounds__(128) void k_pred(const float* __restrict__ pstat,
                                              float* __restrict__ pstat2) {
    const int t = threadIdx.x;
    const float* p = pstat + (size_t)blockIdx.x * 100 * 2 * DD;
    float a0 = 0.f, a1 = 0.f, a2 = 0.f, a3 = 0.f;
    for (int r = 0; r < 100; r += 4) {
        a0 += p[(r + 0) * 2 * DD + t];
        a1 += p[(r + 1) * 2 * DD + t];
        a2 += p[(r + 2) * 2 * DD + t];
        a3 += p[(r + 3) * 2 * DD + t];
    }
    pstat2[blockIdx.x * 2 * DD + t] = (a0 + a1) + (a2 + a3);
}

// ---------------- K8: reduce 125 rows + fold into scale/shift ----------------
__global__ __launch_bounds__(128) void k_finstats(const float* __restrict__ pstat2,
                                                  float* __restrict__ ss,
                                                  const float* __restrict__ gamma,
                                                  const float* __restrict__ beta) {
    const int t = threadIdx.x;
    float acc = 0.f;
    for (int b = 0; b < PRED_BLOCKS; ++b)
        acc += pstat2[b * 2 * DD + t];
    __shared__ float red[2 * DD];
    red[t] = acc;
    __syncthreads();
    if (t < DD) {
        const float invn = 1.0f / NN;
        float mean = red[t] * invn;
        float var = fmaxf(red[DD + t] * invn - mean * mean, 0.f);
        float sc = rsqrtf(var + 1e-5f) * gamma[t];
        ss[t] = sc;
        ss[DD + t] = beta[t] - mean * sc;
    }
}

// ---------------- K9: out = relu(out*scale + shift) in-place ----------------
__global__ __launch_bounds__(256) void k_final(float* __restrict__ out,
                                               const float* __restrict__ ss) {
    const size_t idx = ((size_t)blockIdx.x * 256 + threadIdx.x) * 4;
    const int c = (int)(idx & 63);
    float4 v = *(const float4*)(out + idx);
    float4 o;
    o.x = fmaxf(fmaf(v.x, ss[c + 0], ss[DD + c + 0]), 0.f);
    o.y = fmaxf(fmaf(v.y, ss[c + 1], ss[DD + c + 1]), 0.f);
    o.z = fmaxf(fmaf(v.z, ss[c + 2], ss[DD + c + 2]), 0.f);
    o.w = fmaxf(fmaf(v.w, ss[c + 3], ss[DD + c + 3]), 0.f);
    *(float4*)(out + idx) = o;
}

extern "C" void kernel_launch(void* const* d_in, const int* in_sizes, int n_in,
                              void* d_out, int out_size, void* d_ws, size_t ws_size,
                              hipStream_t stream) {
    const float* x     = (const float*)d_in[0];
    const int*   esrc  = (const int*)d_in[1];
    const int*   edst  = (const int*)d_in[2];
    const float* ew    = (const float*)d_in[3];
    const float* W     = (const float*)d_in[4];
    // d_in[5] = bias: cancels exactly in batchnorm (shift-invariant) — unused.
    const float* gamma = (const float*)d_in[6];
    const float* beta  = (const float*)d_in[7];
    float*       out   = (float*)d_out;   // doubles as the agg buffer

    char* ws = (char*)d_ws;
    unsigned* support2 = (unsigned*)ws;  ws += (size_t)NN * DD * 2;        // 12.8 MB bf16 packed
    int2*     permA  = (int2*)ws;     ws += (size_t)NE * 8;                // 12.8 MB coarse-grouped
    unsigned* perm   = (unsigned*)ws; ws += (size_t)NE * 4;                // 6.4 MB packed per-node CSR
    int*   lcntT  = (int*)ws;    ws += NCOARSE * LCNT_STRIDE * 4;          // 627 KB count matrix
    int*   cnt    = (int*)ws;    ws += NCOARSE * 4;
    float* ss     = (float*)ws;  ws += 128 * 4;                            // scale|shift
    int*   cstart = (int*)ws;    ws += (NCOARSE + 1) * 4;
    int*   bstart = (int*)ws;    ws += (NN + 4) * 4;                       // per-node CSR offsets
    float* pstat  = (float*)ws;  ws += (size_t)GATHER_BLOCKS * 2 * DD * 4; // 6.4 MB gather partials
    float* pstat2 = (float*)ws;  ws += PRED_BLOCKS * 2 * DD * 4;           // 64 KB stage-2

    k_hist        <<<PLACE_BLOCKS, 256, 0, stream>>>(edst, lcntT);
    k_colscan     <<<NCOARSE, 256, 0, stream>>>(lcntT, cnt);
    k_scan196     <<<1, 256, 0, stream>>>(cnt, cstart, bstart);
    k_gemm_scatter<<<GEMM_TILES + PLACE_BLOCKS, 256, 0, stream>>>(
                      x, W, support2, esrc, edst, ew, cstart, lcntT, permA);
    k_placeB      <<<NCOARSE, 1024, 0, stream>>>(cstart, permA, perm, bstart);
    k_gather      <<<GATHER_BLOCKS, 512, 0, stream>>>(bstart, perm, (const uint4*)support2, out, pstat);
    k_pred        <<<PRED_BLOCKS, 128, 0, stream>>>(pstat, pstat2);
    k_finstats    <<<1, 128, 0, stream>>>(pstat2, ss, gamma, beta);
    k_final       <<<NN * DD / 4 / 256, 256, 0, stream>>>(out, ss);
}

// Round 17
// 215.006 us; speedup vs baseline: 1.0127x; 1.0127x over previous
//
#include <hip/hip_runtime.h>
#include <hip/hip_bf16.h>

#define NN 100000
#define NE 1600000
#define DD 64
#define NCOARSE 196         // 512-node coarse buckets (node>>9)
#define GEMM_TILES 1563     // ceil(NN/64); last tile has 32 rows
#define PLACE_EPB 4096      // 16 edges/thread
#define PLACE_BLOCKS 391    // ceil(NE/4096)
#define LCNT_STRIDE 400     // padded row stride of lcntT
#define STAT_BLOCKS 256

__device__ inline unsigned short f2bf(float f) {
    __hip_bfloat16 h = __float2bfloat16(f);
    unsigned short s; __builtin_memcpy(&s, &h, 2); return s;
}
// decode packed edge: src = p & 0x1FFFF;  w = bf15<<16 (sign 0)
__device__ inline float pw(unsigned p) { return __uint_as_float((p & 0xFFFE0000u) >> 1); }

// ---------------- K1: per-block coarse histogram ----------------
__global__ __launch_bounds__(256) void k_hist(const int* __restrict__ edst,
                                              int* __restrict__ lcntT) {
    __shared__ int h[NCOARSE];
    for (int i = threadIdx.x; i < NCOARSE; i += 256) h[i] = 0;
    __syncthreads();
    const int e0 = blockIdx.x * PLACE_EPB;
#pragma unroll
    for (int k = 0; k < 16; ++k) {
        int e = e0 + k * 256 + threadIdx.x;
        if (e < NE) atomicAdd(&h[edst[e] >> 9], 1);
    }
    __syncthreads();
    for (int i = threadIdx.x; i < NCOARSE; i += 256)
        lcntT[i * LCNT_STRIDE + blockIdx.x] = h[i];
}

// ---------------- K2: in-place exclusive scan of each bucket's block counts ----------------
__global__ __launch_bounds__(256) void k_colscan(int* __restrict__ lcntT,
                                                 int* __restrict__ cnt) {
    int* col = lcntT + blockIdx.x * LCNT_STRIDE;
    const int t = threadIdx.x, base = t * 2;
    int v[2], s = 0;
#pragma unroll
    for (int j = 0; j < 2; ++j) {
        v[j] = (base + j < PLACE_BLOCKS) ? col[base + j] : 0;
        s += v[j];
    }
    __shared__ int sc[256];
    sc[t] = s; __syncthreads();
    for (int o = 1; o < 256; o <<= 1) {
        int u = (t >= o) ? sc[t - o] : 0;
        __syncthreads();
        sc[t] += u;
        __syncthreads();
    }
    int run = sc[t] - s;
#pragma unroll
    for (int j = 0; j < 2; ++j) {
        if (base + j < PLACE_BLOCKS) col[base + j] = run;
        run += v[j];
    }
    if (t == 255) cnt[blockIdx.x] = sc[255];
}

// ---------------- K3: exclusive scan of 196 coarse totals ----------------
__global__ __launch_bounds__(256) void k_scan196(const int* __restrict__ cnt,
                                                 int* __restrict__ cstart,
                                                 int* __restrict__ bstart) {
    __shared__ int sc[256];
    const int t = threadIdx.x;
    const int v = (t < NCOARSE) ? cnt[t] : 0;
    sc[t] = v; __syncthreads();
    for (int o = 1; o < 256; o <<= 1) {
        int u = (t >= o) ? sc[t - o] : 0;
        __syncthreads();
        sc[t] += u;
        __syncthreads();
    }
    if (t < NCOARSE) cstart[t] = sc[t] - v;
    if (t == 0) { cstart[NCOARSE] = NE; bstart[NN] = NE; }
}

// ---------------- K4: fused  support = x@W (64-row tiles)  +  edge scatter (EPB 4096) ----------------
__global__ __launch_bounds__(256) void k_gemm_scatter(const float* __restrict__ x,
                                                      const float* __restrict__ Wg,
                                                      unsigned* __restrict__ support2,
                                                      const int* __restrict__ esrc,
                                                      const int* __restrict__ edst,
                                                      const float* __restrict__ ew,
                                                      const int* __restrict__ cstart,
                                                      const int* __restrict__ lcntT,
                                                      int2* __restrict__ permA) {
    if (blockIdx.x >= GEMM_TILES) {
        const int blk = blockIdx.x - GEMM_TILES;     // 0..390
        __shared__ int loff[NCOARSE];
        for (int i = threadIdx.x; i < NCOARSE; i += 256)
            loff[i] = cstart[i] + lcntT[i * LCNT_STRIDE + blk];
        __syncthreads();
        const int e0 = blk * PLACE_EPB;
#pragma unroll
        for (int k = 0; k < 16; ++k) {
            int e = e0 + k * 256 + threadIdx.x;
            if (e < NE) {
                int d = edst[e];
                int p = atomicAdd(&loff[d >> 9], 1);
                permA[p] = make_int2(esrc[e] | ((d & 511) << 17), __float_as_int(ew[e]));
            }
        }
        return;
    }

    __shared__ float Ws[DD * DD];   // 16 KB
    __shared__ float Xs[64 * DD];   // 16 KB
    const int r0 = blockIdx.x * 64;
    const int nrows = (r0 + 64 <= NN) ? 64 : (NN - r0);

    for (int i = threadIdx.x; i < DD * DD / 4; i += 256)
        ((float4*)Ws)[i] = ((const float4*)Wg)[i];
    const float4* xg = (const float4*)(x + (size_t)r0 * DD);
    for (int i = threadIdx.x; i < nrows * 16; i += 256)
        ((float4*)Xs)[i] = xg[i];
    __syncthreads();

    const int wave = threadIdx.x >> 6, lane = threadIdx.x & 63;
    const int half = lane >> 5, hl = lane & 31;
    const int rbase = wave * 16 + half * 8;

    float acc0[8] = {0.f, 0.f, 0.f, 0.f, 0.f, 0.f, 0.f, 0.f};
    float acc1[8] = {0.f, 0.f, 0.f, 0.f, 0.f, 0.f, 0.f, 0.f};
#pragma unroll 4
    for (int k = 0; k < DD; k += 4) {
        float2 w0 = *(const float2*)&Ws[(k + 0) * DD + 2 * hl];
        float2 w1 = *(const float2*)&Ws[(k + 1) * DD + 2 * hl];
        float2 w2 = *(const float2*)&Ws[(k + 2) * DD + 2 * hl];
        float2 w3 = *(const float2*)&Ws[(k + 3) * DD + 2 * hl];
#pragma unroll
        for (int r = 0; r < 8; ++r) {
            float4 xv = *(const float4*)&Xs[(rbase + r) * DD + k];
            acc0[r] = fmaf(xv.x, w0.x, acc0[r]); acc1[r] = fmaf(xv.x, w0.y, acc1[r]);
            acc0[r] = fmaf(xv.y, w1.x, acc0[r]); acc1[r] = fmaf(xv.y, w1.y, acc1[r]);
            acc0[r] = fmaf(xv.z, w2.x, acc0[r]); acc1[r] = fmaf(xv.z, w2.y, acc1[r]);
            acc0[r] = fmaf(xv.w, w3.x, acc0[r]); acc1[r] = fmaf(xv.w, w3.y, acc1[r]);
        }
    }
#pragma unroll
    for (int r = 0; r < 8; ++r) {
        const int row = rbase + r;
        if (row < nrows) {
            unsigned p = (unsigned)f2bf(acc0[r]) | ((unsigned)f2bf(acc1[r]) << 16);
            support2[(size_t)(r0 + row) * 32 + hl] = p;
        }
    }
}

// ---------------- K5: placeB — per-node CSR within 512-node bucket; 4B packed entries ----------------
__global__ __launch_bounds__(1024) void k_placeB(const int* __restrict__ cstart,
                                                 const int2* __restrict__ permA,
                                                 unsigned* __restrict__ perm,
                                                 int* __restrict__ bstart) {
    __shared__ int sc[512], loff[512], wtot[8];
    const int c = blockIdx.x, t = threadIdx.x;
    const int wave = t >> 6, lane = t & 63;
    const int cs = cstart[c], ce = cstart[c + 1];
    if (t < 512) sc[t] = 0;
    __syncthreads();
    for (int j = cs + t; j < ce; j += 1024)
        atomicAdd(&sc[(permA[j].x >> 17) & 511], 1);
    __syncthreads();
    int v = 0, xv = 0;
    if (wave < 8) {
        v = sc[t];
        xv = v;
#pragma unroll
        for (int o = 1; o < 64; o <<= 1) {
            int u = __shfl_up(xv, o, 64);
            if (lane >= o) xv += u;
        }
        if (lane == 63) wtot[wave] = xv;
    }
    __syncthreads();
    if (t < 8) {
        int w = wtot[t], xw = w;
#pragma unroll
        for (int o = 1; o < 8; o <<= 1) {
            int u = __shfl_up(xw, o, 64);
            if (t >= o) xw += u;
        }
        wtot[t] = xw - w;
    }
    __syncthreads();
    if (wave < 8) {
        const int base = cs + wtot[wave] + xv - v;
        loff[t] = base;
        const int node = c * 512 + t;
        if (node < NN) bstart[node] = base;
    }
    __syncthreads();
    for (int j = cs + t; j < ce; j += 1024) {
        int2 m = permA[j];
        int p = atomicAdd(&loff[(m.x >> 17) & 511], 1);
        unsigned wb = (unsigned)(f2bf(__int_as_float(m.y)) & 0x7FFF);   // bf16-RNE, sign 0
        perm[p] = (unsigned)(m.x & 0x1FFFF) | (wb << 17);
    }
}

// ---------------- K6: gather — 512 thr (8 waves), wave per node, uint4 loads ----------------
__global__ __launch_bounds__(512) void k_gather(const int* __restrict__ bstart,
                                                const unsigned* __restrict__ perm,
                                                const uint4* __restrict__ support4,
                                                float* __restrict__ out) {
    const int wave = threadIdx.x >> 6, lane = threadIdx.x & 63;
    const int sub = lane >> 3, q = lane & 7;
    const int d = blockIdx.x * 8 + wave;            // grid = NN/8 exactly
    const int bs = bstart[d], be = bstart[d + 1];
    float acc[8] = {0.f, 0.f, 0.f, 0.f, 0.f, 0.f, 0.f, 0.f};
    int j0 = bs;
    for (; j0 + 15 < be; j0 += 16) {
        unsigned mA = perm[j0 + sub];
        unsigned mB = perm[j0 + 8 + sub];
        uint4 pA = support4[(size_t)(mA & 0x1FFFF) * 8 + q];
        uint4 pB = support4[(size_t)(mB & 0x1FFFF) * 8 + q];
        float wA = pw(mA), wB = pw(mB);
        acc[0] = fmaf(wA, __uint_as_float(pA.x << 16), acc[0]);
        acc[1] = fmaf(wA, __uint_as_float(pA.x & 0xffff0000u), acc[1]);
        acc[2] = fmaf(wA, __uint_as_float(pA.y << 16), acc[2]);
        acc[3] = fmaf(wA, __uint_as_float(pA.y & 0xffff0000u), acc[3]);
        acc[4] = fmaf(wA, __uint_as_float(pA.z << 16), acc[4]);
        acc[5] = fmaf(wA, __uint_as_float(pA.z & 0xffff0000u), acc[5]);
        acc[6] = fmaf(wA, __uint_as_float(pA.w << 16), acc[6]);
        acc[7] = fmaf(wA, __uint_as_float(pA.w & 0xffff0000u), acc[7]);
        acc[0] = fmaf(wB, __uint_as_float(pB.x << 16), acc[0]);
        acc[1] = fmaf(wB, __uint_as_float(pB.x & 0xffff0000u), acc[1]);
        acc[2] = fmaf(wB, __uint_as_float(pB.y << 16), acc[2]);
        acc[3] = fmaf(wB, __uint_as_float(pB.y & 0xffff0000u), acc[3]);
        acc[4] = fmaf(wB, __uint_as_float(pB.z << 16), acc[4]);
        acc[5] = fmaf(wB, __uint_as_float(pB.z & 0xffff0000u), acc[5]);
        acc[6] = fmaf(wB, __uint_as_float(pB.w << 16), acc[6]);
        acc[7] = fmaf(wB, __uint_as_float(pB.w & 0xffff0000u), acc[7]);
    }
    for (; j0 < be; j0 += 8) {
        if (j0 + sub < be) {
            unsigned m = perm[j0 + sub];
            uint4 p = support4[(size_t)(m & 0x1FFFF) * 8 + q];
            float w = pw(m);
            acc[0] = fmaf(w, __uint_as_float(p.x << 16), acc[0]);
            acc[1] = fmaf(w, __uint_as_float(p.x & 0xffff0000u), acc[1]);
            acc[2] = fmaf(w, __uint_as_float(p.y << 16), acc[2]);
            acc[3] = fmaf(w, __uint_as_float(p.y & 0xffff0000u), acc[3]);
            acc[4] = fmaf(w, __uint_as_float(p.z << 16), acc[4]);
            acc[5] = fmaf(w, __uint_as_float(p.z & 0xffff0000u), acc[5]);
            acc[6] = fmaf(w, __uint_as_float(p.w << 16), acc[6]);
            acc[7] = fmaf(w, __uint_as_float(p.w & 0xffff0000u), acc[7]);
        }
    }
#pragma unroll
    for (int i = 0; i < 8; ++i) {
        acc[i] += __shfl_xor(acc[i], 8, 64);
        acc[i] += __shfl_xor(acc[i], 16, 64);
        acc[i] += __shfl_xor(acc[i], 32, 64);
    }
    if (sub == 0) {
        float* op = out + (size_t)d * DD + q * 8;
        *(float4*)op = make_float4(acc[0], acc[1], acc[2], acc[3]);
        *(float4*)(op + 4) = make_float4(acc[4], acc[5], acc[6], acc[7]);
    }
}

// ---------------- K7: per-column sum & sumsq -> per-block partials ----------------
__device__ inline float4 shfl_down4(float4 v, int dd) {
    v.x = __shfl_down(v.x, dd, 64); v.y = __shfl_down(v.y, dd, 64);
    v.z = __shfl_down(v.z, dd, 64); v.w = __shfl_down(v.w, dd, 64);
    return v;
}
__device__ inline float4 add4(float4 a, float4 b) {
    a.x += b.x; a.y += b.y; a.z += b.z; a.w += b.w; return a;
}

__global__ __launch_bounds__(256) void k_stats(const float* __restrict__ agg,
                                               float* __restrict__ pstat) {
    const int lane = threadIdx.x & 63, wave = threadIdx.x >> 6;
    const int q = lane & 15, sub = lane >> 4;
    float4 s = {0, 0, 0, 0}, sq = {0, 0, 0, 0};
    const int stride = gridDim.x * 16;
    for (int row = (blockIdx.x * 4 + wave) * 4 + sub; row < NN; row += stride) {
        float4 v = *(const float4*)(agg + (size_t)row * DD + q * 4);
        s.x += v.x; s.y += v.y; s.z += v.z; s.w += v.w;
        sq.x = fmaf(v.x, v.x, sq.x); sq.y = fmaf(v.y, v.y, sq.y);
        sq.z = fmaf(v.z, v.z, sq.z); sq.w = fmaf(v.w, v.w, sq.w);
    }
    s = add4(s, shfl_down4(s, 32));  s = add4(s, shfl_down4(s, 16));
    sq = add4(sq, shfl_down4(sq, 32)); sq = add4(sq, shfl_down4(sq, 16));

    __shared__ float red[2][4][DD];
    if (lane < 16) {
        red[0][wave][q * 4 + 0] = s.x;  red[0][wave][q * 4 + 1] = s.y;
        red[0][wave][q * 4 + 2] = s.z;  red[0][wave][q * 4 + 3] = s.w;
        red[1][wave][q * 4 + 0] = sq.x; red[1][wave][q * 4 + 1] = sq.y;
        red[1][wave][q * 4 + 2] = sq.z; red[1][wave][q * 4 + 3] = sq.w;
    }
    __syncthreads();
    if (threadIdx.x < 2 * DD) {
        const int t = threadIdx.x;
        const int part = t >> 6, c = t & 63;
        pstat[blockIdx.x * 2 * DD + t] =
            red[part][0][c] + red[part][1][c] + red[part][2][c] + red[part][3][c];
    }
}

// ---------------- K8: reduce partials + fold into scale/shift ----------------
__global__ __launch_bounds__(128) void k_finstats(const float* __restrict__ pstat,
                                                  float* __restrict__ ss,
                                                  const float* __restrict__ gamma,
                                                  const float* __restrict__ beta) {
    const int t = threadIdx.x;
    float acc = 0.f;
    for (int b = 0; b < STAT_BLOCKS; ++b)
        acc += pstat[b * 2 * DD + t];
    __shared__ float red[2 * DD];
    red[t] = acc;
    __syncthreads();
    if (t < DD) {
        const float invn = 1.0f / NN;
        float mean = red[t] * invn;
        float var = fmaxf(red[DD + t] * invn - mean * mean, 0.f);
        float sc = rsqrtf(var + 1e-5f) * gamma[t];
        ss[t] = sc;
        ss[DD + t] = beta[t] - mean * sc;
    }
}

// ---------------- K9: out = relu(out*scale + shift) in-place ----------------
__global__ __launch_bounds__(256) void k_final(float* __restrict__ out,
                                               const float* __restrict__ ss) {
    const size_t idx = ((size_t)blockIdx.x * 256 + threadIdx.x) * 4;
    const int c = (int)(idx & 63);
    float4 v = *(const float4*)(out + idx);
    float4 o;
    o.x = fmaxf(fmaf(v.x, ss[c + 0], ss[DD + c + 0]), 0.f);
    o.y = fmaxf(fmaf(v.y, ss[c + 1], ss[DD + c + 1]), 0.f);
    o.z = fmaxf(fmaf(v.z, ss[c + 2], ss[DD + c + 2]), 0.f);
    o.w = fmaxf(fmaf(v.w, ss[c + 3], ss[DD + c + 3]), 0.f);
    *(float4*)(out + idx) = o;
}

extern "C" void kernel_launch(void* const* d_in, const int* in_sizes, int n_in,
                              void* d_out, int out_size, void* d_ws, size_t ws_size,
                              hipStream_t stream) {
    const float* x     = (const float*)d_in[0];
    const int*   esrc  = (const int*)d_in[1];
    const int*   edst  = (const int*)d_in[2];
    const float* ew    = (const float*)d_in[3];
    const float* W     = (const float*)d_in[4];
    // d_in[5] = bias: cancels exactly in batchnorm (shift-invariant) — unused.
    const float* gamma = (const float*)d_in[6];
    const float* beta  = (const float*)d_in[7];
    float*       out   = (float*)d_out;   // doubles as the agg buffer

    char* ws = (char*)d_ws;
    unsigned* support2 = (unsigned*)ws;  ws += (size_t)NN * DD * 2;        // 12.8 MB bf16 packed
    int2*     permA  = (int2*)ws;     ws += (size_t)NE * 8;                // 12.8 MB coarse-grouped
    unsigned* perm   = (unsigned*)ws; ws += (size_t)NE * 4;                // 6.4 MB packed per-node CSR
    int*   lcntT  = (int*)ws;    ws += NCOARSE * LCNT_STRIDE * 4;          // 313 KB count matrix
    int*   cnt    = (int*)ws;    ws += NCOARSE * 4;
    float* ss     = (float*)ws;  ws += 128 * 4;                            // scale|shift
    int*   cstart = (int*)ws;    ws += (NCOARSE + 1) * 4;
    int*   bstart = (int*)ws;    ws += (NN + 4) * 4;                       // per-node CSR offsets
    float* pstat  = (float*)ws;  ws += STAT_BLOCKS * 2 * DD * 4;           // 128 KB partials

    k_hist        <<<PLACE_BLOCKS, 256, 0, stream>>>(edst, lcntT);
    k_colscan     <<<NCOARSE, 256, 0, stream>>>(lcntT, cnt);
    k_scan196     <<<1, 256, 0, stream>>>(cnt, cstart, bstart);
    k_gemm_scatter<<<GEMM_TILES + PLACE_BLOCKS, 256, 0, stream>>>(
                      x, W, support2, esrc, edst, ew, cstart, lcntT, permA);
    k_placeB      <<<NCOARSE, 1024, 0, stream>>>(cstart, permA, perm, bstart);
    k_gather      <<<NN / 8, 512, 0, stream>>>(bstart, perm, (const uint4*)support2, out);
    k_stats       <<<STAT_BLOCKS, 256, 0, stream>>>(out, pstat);
    k_finstats    <<<1, 128, 0, stream>>>(pstat, ss, gamma, beta);
    k_final       <<<NN * DD / 4 / 256, 256, 0, stream>>>(out, ss);
}

// Round 18
// 204.922 us; speedup vs baseline: 1.0625x; 1.0492x over previous
//
#include <hip/hip_runtime.h>
#include <hip/hip_bf16.h>

#define NN 100000
#define NE 1600000
#define DD 64
#define NCOARSE 392         // 256-node coarse buckets (node>>8)
#define GEMM_TILES 1563     // ceil(NN/64); last tile has 32 rows
#define PLACE_EPB 8192      // 32 edges/thread
#define PLACE_BLOCKS 196    // ceil(NE/8192)
#define LCNT_STRIDE 200     // padded row stride of lcntT
#define STAT_BLOCKS 256

__device__ inline unsigned short f2bf(float f) {
    __hip_bfloat16 h = __float2bfloat16(f);
    unsigned short s; __builtin_memcpy(&s, &h, 2); return s;
}
// decode packed edge: src = p & 0x1FFFF;  w = bf15<<16 (sign 0)
__device__ inline float pw(unsigned p) { return __uint_as_float((p & 0xFFFE0000u) >> 1); }

// ---------------- K1: per-block coarse histogram ----------------
__global__ __launch_bounds__(256) void k_hist(const int* __restrict__ edst,
                                              int* __restrict__ lcntT) {
    __shared__ int h[NCOARSE];
    for (int i = threadIdx.x; i < NCOARSE; i += 256) h[i] = 0;
    __syncthreads();
    const int e0 = blockIdx.x * PLACE_EPB;
#pragma unroll
    for (int k = 0; k < 32; ++k) {
        int e = e0 + k * 256 + threadIdx.x;
        if (e < NE) atomicAdd(&h[edst[e] >> 8], 1);
    }
    __syncthreads();
    for (int i = threadIdx.x; i < NCOARSE; i += 256)
        lcntT[i * LCNT_STRIDE + blockIdx.x] = h[i];
}

// ---------------- K2: in-place exclusive scan of each bucket's block counts ----------------
__global__ __launch_bounds__(256) void k_colscan(int* __restrict__ lcntT,
                                                 int* __restrict__ cnt) {
    int* col = lcntT + blockIdx.x * LCNT_STRIDE;
    const int t = threadIdx.x;
    const int v = (t < PLACE_BLOCKS) ? col[t] : 0;
    __shared__ int sc[256];
    sc[t] = v; __syncthreads();
    for (int o = 1; o < 256; o <<= 1) {
        int u = (t >= o) ? sc[t - o] : 0;
        __syncthreads();
        sc[t] += u;
        __syncthreads();
    }
    if (t < PLACE_BLOCKS) col[t] = sc[t] - v;
    if (t == 255) cnt[blockIdx.x] = sc[255];
}

// ---------------- K3: exclusive scan of 392 coarse totals ----------------
__global__ __launch_bounds__(512) void k_scan392(const int* __restrict__ cnt,
                                                 int* __restrict__ cstart,
                                                 int* __restrict__ bstart) {
    __shared__ int sc[512];
    const int t = threadIdx.x;
    const int v = (t < NCOARSE) ? cnt[t] : 0;
    sc[t] = v; __syncthreads();
    for (int o = 1; o < 512; o <<= 1) {
        int u = (t >= o) ? sc[t - o] : 0;
        __syncthreads();
        sc[t] += u;
        __syncthreads();
    }
    if (t < NCOARSE) cstart[t] = sc[t] - v;
    if (t == 0) { cstart[NCOARSE] = NE; bstart[NN] = NE; }
}

// ---------------- K4: fused  edge scatter (blocks [0,196))  +  support = x@W (rest) ----------------
// Scatter blocks first in dispatch order: latency-bound half spreads across CUs
// immediately and overlaps the VALU-bound GEMM for its entire duration.
__global__ __launch_bounds__(256) void k_gemm_scatter(const float* __restrict__ x,
                                                      const float* __restrict__ Wg,
                                                      unsigned* __restrict__ support2,
                                                      const int* __restrict__ esrc,
                                                      const int* __restrict__ edst,
                                                      const float* __restrict__ ew,
                                                      const int* __restrict__ cstart,
                                                      const int* __restrict__ lcntT,
                                                      int2* __restrict__ permA) {
    if (blockIdx.x < PLACE_BLOCKS) {
        const int blk = blockIdx.x;
        __shared__ int loff[NCOARSE];
        for (int i = threadIdx.x; i < NCOARSE; i += 256)
            loff[i] = cstart[i] + lcntT[i * LCNT_STRIDE + blk];
        __syncthreads();
        const int e0 = blk * PLACE_EPB;
#pragma unroll
        for (int k = 0; k < 32; ++k) {
            int e = e0 + k * 256 + threadIdx.x;
            if (e < NE) {
                int d = edst[e];
                int p = atomicAdd(&loff[d >> 8], 1);
                permA[p] = make_int2(esrc[e] | ((d & 255) << 17), __float_as_int(ew[e]));
            }
        }
        return;
    }

    __shared__ float Ws[DD * DD];   // 16 KB
    __shared__ float Xs[64 * DD];   // 16 KB
    const int r0 = (blockIdx.x - PLACE_BLOCKS) * 64;
    const int nrows = (r0 + 64 <= NN) ? 64 : (NN - r0);

    for (int i = threadIdx.x; i < DD * DD / 4; i += 256)
        ((float4*)Ws)[i] = ((const float4*)Wg)[i];
    const float4* xg = (const float4*)(x + (size_t)r0 * DD);
    for (int i = threadIdx.x; i < nrows * 16; i += 256)
        ((float4*)Xs)[i] = xg[i];
    __syncthreads();

    const int wave = threadIdx.x >> 6, lane = threadIdx.x & 63;
    const int half = lane >> 5, hl = lane & 31;
    const int rbase = wave * 16 + half * 8;

    float acc0[8] = {0.f, 0.f, 0.f, 0.f, 0.f, 0.f, 0.f, 0.f};
    float acc1[8] = {0.f, 0.f, 0.f, 0.f, 0.f, 0.f, 0.f, 0.f};
#pragma unroll 4
    for (int k = 0; k < DD; k += 4) {
        float2 w0 = *(const float2*)&Ws[(k + 0) * DD + 2 * hl];
        float2 w1 = *(const float2*)&Ws[(k + 1) * DD + 2 * hl];
        float2 w2 = *(const float2*)&Ws[(k + 2) * DD + 2 * hl];
        float2 w3 = *(const float2*)&Ws[(k + 3) * DD + 2 * hl];
#pragma unroll
        for (int r = 0; r < 8; ++r) {
            float4 xv = *(const float4*)&Xs[(rbase + r) * DD + k];
            acc0[r] = fmaf(xv.x, w0.x, acc0[r]); acc1[r] = fmaf(xv.x, w0.y, acc1[r]);
            acc0[r] = fmaf(xv.y, w1.x, acc0[r]); acc1[r] = fmaf(xv.y, w1.y, acc1[r]);
            acc0[r] = fmaf(xv.z, w2.x, acc0[r]); acc1[r] = fmaf(xv.z, w2.y, acc1[r]);
            acc0[r] = fmaf(xv.w, w3.x, acc0[r]); acc1[r] = fmaf(xv.w, w3.y, acc1[r]);
        }
    }
#pragma unroll
    for (int r = 0; r < 8; ++r) {
        const int row = rbase + r;
        if (row < nrows) {
            unsigned p = (unsigned)f2bf(acc0[r]) | ((unsigned)f2bf(acc1[r]) << 16);
            support2[(size_t)(r0 + row) * 32 + hl] = p;
        }
    }
}

// ---------------- K5: placeB — per-node CSR within 256-node bucket; 4B packed entries ----------------
__global__ __launch_bounds__(1024) void k_placeB(const int* __restrict__ cstart,
                                                 const int2* __restrict__ permA,
                                                 unsigned* __restrict__ perm,
                                                 int* __restrict__ bstart) {
    __shared__ int sc[256], loff[256], wtot[4];
    const int c = blockIdx.x, t = threadIdx.x;
    const int wave = t >> 6, lane = t & 63;
    const int cs = cstart[c], ce = cstart[c + 1];
    if (t < 256) sc[t] = 0;
    __syncthreads();
    for (int j = cs + t; j < ce; j += 1024)
        atomicAdd(&sc[(permA[j].x >> 17) & 255], 1);
    __syncthreads();
    int v = 0, xv = 0;
    if (wave < 4) {                   // t < 256
        v = sc[t];
        xv = v;
#pragma unroll
        for (int o = 1; o < 64; o <<= 1) {
            int u = __shfl_up(xv, o, 64);
            if (lane >= o) xv += u;
        }
        if (lane == 63) wtot[wave] = xv;
    }
    __syncthreads();
    if (t < 4) {
        int w = wtot[t], xw = w;
#pragma unroll
        for (int o = 1; o < 4; o <<= 1) {
            int u = __shfl_up(xw, o, 64);
            if (t >= o) xw += u;
        }
        wtot[t] = xw - w;
    }
    __syncthreads();
    if (wave < 4) {
        const int base = cs + wtot[wave] + xv - v;
        loff[t] = base;
        const int node = c * 256 + t;
        if (node < NN) bstart[node] = base;
    }
    __syncthreads();
    for (int j = cs + t; j < ce; j += 1024) {
        int2 m = permA[j];
        int p = atomicAdd(&loff[(m.x >> 17) & 255], 1);
        unsigned wb = (unsigned)(f2bf(__int_as_float(m.y)) & 0x7FFF);   // bf16-RNE, sign 0
        perm[p] = (unsigned)(m.x & 0x1FFFF) | (wb << 17);
    }
}

// ---------------- K6: gather — 512 thr (8 waves), wave per node, uint4 loads ----------------
__global__ __launch_bounds__(512) void k_gather(const int* __restrict__ bstart,
                                                const unsigned* __restrict__ perm,
                                                const uint4* __restrict__ support4,
                                                float* __restrict__ out) {
    const int wave = threadIdx.x >> 6, lane = threadIdx.x & 63;
    const int sub = lane >> 3, q = lane & 7;
    const int d = blockIdx.x * 8 + wave;            // grid = NN/8 exactly
    const int bs = bstart[d], be = bstart[d + 1];
    float acc[8] = {0.f, 0.f, 0.f, 0.f, 0.f, 0.f, 0.f, 0.f};
    int j0 = bs;
    for (; j0 + 15 < be; j0 += 16) {
        unsigned mA = perm[j0 + sub];
        unsigned mB = perm[j0 + 8 + sub];
        uint4 pA = support4[(size_t)(mA & 0x1FFFF) * 8 + q];
        uint4 pB = support4[(size_t)(mB & 0x1FFFF) * 8 + q];
        float wA = pw(mA), wB = pw(mB);
        acc[0] = fmaf(wA, __uint_as_float(pA.x << 16), acc[0]);
        acc[1] = fmaf(wA, __uint_as_float(pA.x & 0xffff0000u), acc[1]);
        acc[2] = fmaf(wA, __uint_as_float(pA.y << 16), acc[2]);
        acc[3] = fmaf(wA, __uint_as_float(pA.y & 0xffff0000u), acc[3]);
        acc[4] = fmaf(wA, __uint_as_float(pA.z << 16), acc[4]);
        acc[5] = fmaf(wA, __uint_as_float(pA.z & 0xffff0000u), acc[5]);
        acc[6] = fmaf(wA, __uint_as_float(pA.w << 16), acc[6]);
        acc[7] = fmaf(wA, __uint_as_float(pA.w & 0xffff0000u), acc[7]);
        acc[0] = fmaf(wB, __uint_as_float(pB.x << 16), acc[0]);
        acc[1] = fmaf(wB, __uint_as_float(pB.x & 0xffff0000u), acc[1]);
        acc[2] = fmaf(wB, __uint_as_float(pB.y << 16), acc[2]);
        acc[3] = fmaf(wB, __uint_as_float(pB.y & 0xffff0000u), acc[3]);
        acc[4] = fmaf(wB, __uint_as_float(pB.z << 16), acc[4]);
        acc[5] = fmaf(wB, __uint_as_float(pB.z & 0xffff0000u), acc[5]);
        acc[6] = fmaf(wB, __uint_as_float(pB.w << 16), acc[6]);
        acc[7] = fmaf(wB, __uint_as_float(pB.w & 0xffff0000u), acc[7]);
    }
    for (; j0 < be; j0 += 8) {
        if (j0 + sub < be) {
            unsigned m = perm[j0 + sub];
            uint4 p = support4[(size_t)(m & 0x1FFFF) * 8 + q];
            float w = pw(m);
            acc[0] = fmaf(w, __uint_as_float(p.x << 16), acc[0]);
            acc[1] = fmaf(w, __uint_as_float(p.x & 0xffff0000u), acc[1]);
            acc[2] = fmaf(w, __uint_as_float(p.y << 16), acc[2]);
            acc[3] = fmaf(w, __uint_as_float(p.y & 0xffff0000u), acc[3]);
            acc[4] = fmaf(w, __uint_as_float(p.z << 16), acc[4]);
            acc[5] = fmaf(w, __uint_as_float(p.z & 0xffff0000u), acc[5]);
            acc[6] = fmaf(w, __uint_as_float(p.w << 16), acc[6]);
            acc[7] = fmaf(w, __uint_as_float(p.w & 0xffff0000u), acc[7]);
        }
    }
#pragma unroll
    for (int i = 0; i < 8; ++i) {
        acc[i] += __shfl_xor(acc[i], 8, 64);
        acc[i] += __shfl_xor(acc[i], 16, 64);
        acc[i] += __shfl_xor(acc[i], 32, 64);
    }
    if (sub == 0) {
        float* op = out + (size_t)d * DD + q * 8;
        *(float4*)op = make_float4(acc[0], acc[1], acc[2], acc[3]);
        *(float4*)(op + 4) = make_float4(acc[4], acc[5], acc[6], acc[7]);
    }
}

// ---------------- K7: per-column sum & sumsq -> per-block partials ----------------
__device__ inline float4 shfl_down4(float4 v, int dd) {
    v.x = __shfl_down(v.x, dd, 64); v.y = __shfl_down(v.y, dd, 64);
    v.z = __shfl_down(v.z, dd, 64); v.w = __shfl_down(v.w, dd, 64);
    return v;
}
__device__ inline float4 add4(float4 a, float4 b) {
    a.x += b.x; a.y += b.y; a.z += b.z; a.w += b.w; return a;
}

__global__ __launch_bounds__(256) void k_stats(const float* __restrict__ agg,
                                               float* __restrict__ pstat) {
    const int lane = threadIdx.x & 63, wave = threadIdx.x >> 6;
    const int q = lane & 15, sub = lane >> 4;
    float4 s = {0, 0, 0, 0}, sq = {0, 0, 0, 0};
    const int stride = gridDim.x * 16;
    for (int row = (blockIdx.x * 4 + wave) * 4 + sub; row < NN; row += stride) {
        float4 v = *(const float4*)(agg + (size_t)row * DD + q * 4);
        s.x += v.x; s.y += v.y; s.z += v.z; s.w += v.w;
        sq.x = fmaf(v.x, v.x, sq.x); sq.y = fmaf(v.y, v.y, sq.y);
        sq.z = fmaf(v.z, v.z, sq.z); sq.w = fmaf(v.w, v.w, sq.w);
    }
    s = add4(s, shfl_down4(s, 32));  s = add4(s, shfl_down4(s, 16));
    sq = add4(sq, shfl_down4(sq, 32)); sq = add4(sq, shfl_down4(sq, 16));

    __shared__ float red[2][4][DD];
    if (lane < 16) {
        red[0][wave][q * 4 + 0] = s.x;  red[0][wave][q * 4 + 1] = s.y;
        red[0][wave][q * 4 + 2] = s.z;  red[0][wave][q * 4 + 3] = s.w;
        red[1][wave][q * 4 + 0] = sq.x; red[1][wave][q * 4 + 1] = sq.y;
        red[1][wave][q * 4 + 2] = sq.z; red[1][wave][q * 4 + 3] = sq.w;
    }
    __syncthreads();
    if (threadIdx.x < 2 * DD) {
        const int t = threadIdx.x;
        const int part = t >> 6, c = t & 63;
        pstat[blockIdx.x * 2 * DD + t] =
            red[part][0][c] + red[part][1][c] + red[part][2][c] + red[part][3][c];
    }
}

// ---------------- K8: reduce partials + fold into scale/shift ----------------
__global__ __launch_bounds__(128) void k_finstats(const float* __restrict__ pstat,
                                                  float* __restrict__ ss,
                                                  const float* __restrict__ gamma,
                                                  const float* __restrict__ beta) {
    const int t = threadIdx.x;
    float acc = 0.f;
    for (int b = 0; b < STAT_BLOCKS; ++b)
        acc += pstat[b * 2 * DD + t];
    __shared__ float red[2 * DD];
    red[t] = acc;
    __syncthreads();
    if (t < DD) {
        const float invn = 1.0f / NN;
        float mean = red[t] * invn;
        float var = fmaxf(red[DD + t] * invn - mean * mean, 0.f);
        float sc = rsqrtf(var + 1e-5f) * gamma[t];
        ss[t] = sc;
        ss[DD + t] = beta[t] - mean * sc;
    }
}

// ---------------- K9: out = relu(out*scale + shift) in-place ----------------
__global__ __launch_bounds__(256) void k_final(float* __restrict__ out,
                                               const float* __restrict__ ss) {
    const size_t idx = ((size_t)blockIdx.x * 256 + threadIdx.x) * 4;
    const int c = (int)(idx & 63);
    float4 v = *(const float4*)(out + idx);
    float4 o;
    o.x = fmaxf(fmaf(v.x, ss[c + 0], ss[DD + c + 0]), 0.f);
    o.y = fmaxf(fmaf(v.y, ss[c + 1], ss[DD + c + 1]), 0.f);
    o.z = fmaxf(fmaf(v.z, ss[c + 2], ss[DD + c + 2]), 0.f);
    o.w = fmaxf(fmaf(v.w, ss[c + 3], ss[DD + c + 3]), 0.f);
    *(float4*)(out + idx) = o;
}

extern "C" void kernel_launch(void* const* d_in, const int* in_sizes, int n_in,
                              void* d_out, int out_size, void* d_ws, size_t ws_size,
                              hipStream_t stream) {
    const float* x     = (const float*)d_in[0];
    const int*   esrc  = (const int*)d_in[1];
    const int*   edst  = (const int*)d_in[2];
    const float* ew    = (const float*)d_in[3];
    const float* W     = (const float*)d_in[4];
    // d_in[5] = bias: cancels exactly in batchnorm (shift-invariant) — unused.
    const float* gamma = (const float*)d_in[6];
    const float* beta  = (const float*)d_in[7];
    float*       out   = (float*)d_out;   // doubles as the agg buffer

    char* ws = (char*)d_ws;
    unsigned* support2 = (unsigned*)ws;  ws += (size_t)NN * DD * 2;        // 12.8 MB bf16 packed
    int2*     permA  = (int2*)ws;     ws += (size_t)NE * 8;                // 12.8 MB coarse-grouped
    unsigned* perm   = (unsigned*)ws; ws += (size_t)NE * 4;                // 6.4 MB packed per-node CSR
    int*   lcntT  = (int*)ws;    ws += NCOARSE * LCNT_STRIDE * 4;          // 313 KB count matrix
    int*   cnt    = (int*)ws;    ws += NCOARSE * 4;
    float* ss     = (float*)ws;  ws += 128 * 4;                            // scale|shift
    int*   cstart = (int*)ws;    ws += (NCOARSE + 1) * 4;
    int*   bstart = (int*)ws;    ws += (NN + 4) * 4;                       // per-node CSR offsets
    float* pstat  = (float*)ws;  ws += STAT_BLOCKS * 2 * DD * 4;           // 128 KB partials

    k_hist        <<<PLACE_BLOCKS, 256, 0, stream>>>(edst, lcntT);
    k_colscan     <<<NCOARSE, 256, 0, stream>>>(lcntT, cnt);
    k_scan392     <<<1, 512, 0, stream>>>(cnt, cstart, bstart);
    k_gemm_scatter<<<PLACE_BLOCKS + GEMM_TILES, 256, 0, stream>>>(
                      x, W, support2, esrc, edst, ew, cstart, lcntT, permA);
    k_placeB      <<<NCOARSE, 1024, 0, stream>>>(cstart, permA, perm, bstart);
    k_gather      <<<NN / 8, 512, 0, stream>>>(bstart, perm, (const uint4*)support2, out);
    k_stats       <<<STAT_BLOCKS, 256, 0, stream>>>(out, pstat);
    k_finstats    <<<1, 128, 0, stream>>>(pstat, ss, gamma, beta);
    k_final       <<<NN * DD / 4 / 256, 256, 0, stream>>>(out, ss);
}